// Round 1
// baseline (65.865 us; speedup 1.0000x reference)
//
#include <hip/hip_runtime.h>
#include <hip/hip_bf16.h>
#include <stdint.h>

typedef __bf16 v8bf __attribute__((ext_vector_type(8)));
typedef float  v4f  __attribute__((ext_vector_type(4)));

#define LEAK 0.2f

static __device__ __forceinline__ unsigned short bf16rne(float f) {
    union { float f; uint32_t u; } v; v.f = f;
    return (unsigned short)((v.u + 0x7FFFu + ((v.u >> 16) & 1u)) >> 16);
}

// ---------------------------------------------------------------------------
// K0: Wt[c][i] = bf16(W[i][c]),  W:[64][3840] f32,  Wt:[3840][64] bf16
// c = j*60 + l*15 + t  (the original inner flat order of W)
// ---------------------------------------------------------------------------
__global__ __launch_bounds__(256) void k0_wt(const float* __restrict__ W,
                                             unsigned short* __restrict__ Wt) {
    __shared__ float tile[64][65];
    const int c0 = blockIdx.x * 64;      // 60 blocks
    const int t  = threadIdx.x;
    {
        const int cl = t & 63, ig = t >> 6;
#pragma unroll
        for (int r = 0; r < 16; ++r) {
            int i = ig + (r << 2);
            tile[i][cl] = W[i * 3840 + c0 + cl];   // coalesced 256B
        }
    }
    __syncthreads();
    {
        const int il = t & 63, cg = t >> 6;
#pragma unroll
        for (int r = 0; r < 16; ++r) {
            int c = cg + (r << 2);
            Wt[(c0 + c) * 64 + il] = bf16rne(tile[il][c]);  // coalesced 128B
        }
    }
}

// ---------------------------------------------------------------------------
// K1: Yt[j][n*60+lt] = bf16( sum_i x[n,i] * W[i, c=j*60+lt] )
// GEMM: C[n][c] = A[n][i] * B[i][c],  A = x (f32->bf16), B[i][c] = Wt[c][i]
// grid 960 = 16 n-tiles * 60 c-tiles, 256 threads (4 waves)
// ---------------------------------------------------------------------------
__global__ __launch_bounds__(256) void k1_ygemm(const float* __restrict__ x,
                                                const unsigned short* __restrict__ Wt,
                                                unsigned short* __restrict__ Yt) {
    __shared__ unsigned short As[64 * 64];   // [n-local][i]  swizzled
    __shared__ unsigned short Bs[64 * 64];   // [c-local][i]  swizzled
    const int blk = blockIdx.x;
    const int nt = blk / 60, ct = blk % 60;
    const int n0 = nt * 64, c0 = ct * 64;
    const int t = threadIdx.x;
    char* const asb = (char*)As;
    char* const bsb = (char*)Bs;

    // stage A: x rows n0..n0+63, 64 i, f32 -> bf16
#pragma unroll
    for (int r = 0; r < 4; ++r) {
        const int rr = (t >> 4) + (r << 4);          // row 0..63
        const int cq = t & 15;                       // float4 id
        const float4 v = *reinterpret_cast<const float4*>(x + (n0 + rr) * 64 + cq * 4);
        uint2 p;
        p.x = (uint32_t)bf16rne(v.x) | ((uint32_t)bf16rne(v.y) << 16);
        p.y = (uint32_t)bf16rne(v.z) | ((uint32_t)bf16rne(v.w) << 16);
        const int off = rr * 128 + ((cq * 8) ^ ((rr & 7) << 4));
        *reinterpret_cast<uint2*>(asb + off) = p;
    }
    // stage B: Wt rows c0..c0+63 (128B each), straight bf16 copy
#pragma unroll
    for (int r = 0; r < 2; ++r) {
        const int chunk = t + (r << 8);              // 0..511
        const int row = chunk >> 3, c16 = chunk & 7;
        const uint4 v = *reinterpret_cast<const uint4*>(Wt + (c0 + row) * 64 + c16 * 8);
        const int off = row * 128 + ((c16 * 16) ^ ((row & 7) << 4));
        *reinterpret_cast<uint4*>(bsb + off) = v;
    }
    __syncthreads();

    const int w = t >> 6, l = t & 63;
    v4f acc[4];
#pragma unroll
    for (int jt = 0; jt < 4; ++jt) acc[jt] = (v4f){0.f, 0.f, 0.f, 0.f};

#pragma unroll
    for (int s = 0; s < 2; ++s) {
        const int ar = 16 * w + (l & 15);
        const v8bf af = *reinterpret_cast<const v8bf*>(
            asb + ar * 128 + ((64 * s + (l >> 4) * 16) ^ ((ar & 7) << 4)));
#pragma unroll
        for (int jt = 0; jt < 4; ++jt) {
            const int br = 16 * jt + (l & 15);
            const v8bf bf = *reinterpret_cast<const v8bf*>(
                bsb + br * 128 + ((64 * s + (l >> 4) * 16) ^ ((br & 7) << 4)));
            acc[jt] = __builtin_amdgcn_mfma_f32_16x16x32_bf16(af, bf, acc[jt], 0, 0, 0);
        }
    }

    // write C -> Yt[j][n*60+lt], c = j*60+lt
#pragma unroll
    for (int jt = 0; jt < 4; ++jt) {
#pragma unroll
        for (int r = 0; r < 4; ++r) {
            const int n = n0 + 16 * w + (l >> 4) * 4 + r;
            const int c = c0 + jt * 16 + (l & 15);
            const int j = c / 60, lt = c % 60;
            Yt[j * 61440 + n * 60 + lt] = bf16rne(acc[jt][r]);
        }
    }
}

// ---------------------------------------------------------------------------
// K2: split-K main GEMM.  partial[ks][m][j] = sum_{k in chunk} adj[m][k]*Yt[j][k]
// grid 1024 = 16 m-tiles * 64 k-splits, 256 threads, KC=960, BK=64
// ---------------------------------------------------------------------------
__global__ __launch_bounds__(256) void k2_main(const float* __restrict__ adj,
                                               const unsigned short* __restrict__ Yt,
                                               float* __restrict__ partial) {
    __shared__ unsigned short As[64 * 64];   // [m-local][k]  swizzled
    __shared__ unsigned short Bs[64 * 64];   // [j][k]        swizzled
    const int blk = blockIdx.x;
    const int mt = blk >> 6, ks = blk & 63;
    const int m0 = mt * 64;
    const long kc0 = (long)ks * 960;
    const int t = threadIdx.x;
    const int w = t >> 6, l = t & 63;
    char* const asb = (char*)As;
    char* const bsb = (char*)Bs;

    v4f acc[4];
#pragma unroll
    for (int jt = 0; jt < 4; ++jt) acc[jt] = (v4f){0.f, 0.f, 0.f, 0.f};

#pragma unroll 1
    for (int s = 0; s < 15; ++s) {
        const long kb = kc0 + s * 64;
        // stage A: adj rows m0..m0+63 x 64 k, f32 -> bf16
#pragma unroll
        for (int r = 0; r < 4; ++r) {
            const int rr = (t >> 4) + (r << 4);
            const int cq = t & 15;
            const float4 v = *reinterpret_cast<const float4*>(
                adj + (long)(m0 + rr) * 61440 + kb + cq * 4);
            uint2 p;
            p.x = (uint32_t)bf16rne(v.x) | ((uint32_t)bf16rne(v.y) << 16);
            p.y = (uint32_t)bf16rne(v.z) | ((uint32_t)bf16rne(v.w) << 16);
            const int off = rr * 128 + ((cq * 8) ^ ((rr & 7) << 4));
            *reinterpret_cast<uint2*>(asb + off) = p;
        }
        // stage B: Yt rows j=0..63 x 64 k (bf16 straight copy)
#pragma unroll
        for (int r = 0; r < 2; ++r) {
            const int chunk = t + (r << 8);
            const int row = chunk >> 3, c16 = chunk & 7;
            const uint4 v = *reinterpret_cast<const uint4*>(
                Yt + (long)row * 61440 + kb + c16 * 8);
            const int off = row * 128 + ((c16 * 16) ^ ((row & 7) << 4));
            *reinterpret_cast<uint4*>(bsb + off) = v;
        }
        __syncthreads();
#pragma unroll
        for (int ss = 0; ss < 2; ++ss) {
            const int ar = 16 * w + (l & 15);
            const v8bf af = *reinterpret_cast<const v8bf*>(
                asb + ar * 128 + ((64 * ss + (l >> 4) * 16) ^ ((ar & 7) << 4)));
#pragma unroll
            for (int jt = 0; jt < 4; ++jt) {
                const int br = 16 * jt + (l & 15);
                const v8bf bf = *reinterpret_cast<const v8bf*>(
                    bsb + br * 128 + ((64 * ss + (l >> 4) * 16) ^ ((br & 7) << 4)));
                acc[jt] = __builtin_amdgcn_mfma_f32_16x16x32_bf16(af, bf, acc[jt], 0, 0, 0);
            }
        }
        __syncthreads();
    }

    float* const p = partial + (long)ks * 65536;
#pragma unroll
    for (int jt = 0; jt < 4; ++jt) {
#pragma unroll
        for (int r = 0; r < 4; ++r) {
            const int m = m0 + 16 * w + (l >> 4) * 4 + r;
            const int j = jt * 16 + (l & 15);
            p[m * 64 + j] = acc[jt][r];
        }
    }
}

// ---------------------------------------------------------------------------
// K3: out = lrelu( sum_splits partial + x @ W2 )
// ---------------------------------------------------------------------------
__global__ __launch_bounds__(256) void k3_epi(const float* __restrict__ partial,
                                              const float* __restrict__ x,
                                              const float* __restrict__ W2,
                                              float* __restrict__ out) {
    const int idx = blockIdx.x * 256 + threadIdx.x;   // 0..65535
    const int m = idx >> 6, j = idx & 63;
    float s = 0.f;
#pragma unroll 8
    for (int sp = 0; sp < 64; ++sp) s += partial[sp * 65536 + idx];
    float sk = 0.f;
#pragma unroll 8
    for (int i = 0; i < 64; ++i) sk += x[m * 64 + i] * W2[i * 64 + j];
    const float v = s + sk;
    out[idx] = fmaxf(v, LEAK * v);
}

// ---------------------------------------------------------------------------
extern "C" void kernel_launch(void* const* d_in, const int* in_sizes, int n_in,
                              void* d_out, int out_size, void* d_ws, size_t ws_size,
                              hipStream_t stream) {
    const float* x   = (const float*)d_in[0];
    const float* adj = (const float*)d_in[1];
    const float* W   = (const float*)d_in[2];
    const float* W2  = (const float*)d_in[3];
    float* out = (float*)d_out;

    char* ws = (char*)d_ws;
    unsigned short* Wt = (unsigned short*)ws;                  // 491,520 B
    unsigned short* Yt = (unsigned short*)(ws + 524288);       // 7,864,320 B
    float* partial     = (float*)(ws + 8388608);               // 16,777,216 B

    k0_wt   <<<60,   256, 0, stream>>>(W, Wt);
    k1_ygemm<<<960,  256, 0, stream>>>(x, Wt, Yt);
    k2_main <<<1024, 256, 0, stream>>>(adj, Yt, partial);
    k3_epi  <<<256,  256, 0, stream>>>(partial, x, W2, out);
}